// Round 2
// baseline (60.413 us; speedup 1.0000x reference)
//
#include <hip/hip_runtime.h>
#include <math.h>

#define BSZ   65536
#define INP   16
#define HL    10
#define NL    3
#define TT    200
#define NPOP  8600000.0f

__global__ __launch_bounds__(256, 1) void sir_kernel(
    const float* __restrict__ data,   // B x IN
    const float* __restrict__ times,  // T
    const float* __restrict__ W0,     // 3 x HL x IN
    const float* __restrict__ b0,     // 3 x HL
    const float* __restrict__ Wh,     // 3 x NL x HL x HL
    const float* __restrict__ bh,     // 3 x NL x HL
    const float* __restrict__ Wo,     // 3 x 1 x HL
    const float* __restrict__ bo,     // 3 x 1
    float* __restrict__ out)          // T x B
{
    const int tid = threadIdx.x;
    const int b = blockIdx.x * 256 + tid;

    // ---- input row: 4x float4, coalesced ----
    float x[INP];
    const float4* xin = reinterpret_cast<const float4*>(data + (size_t)b * INP);
    #pragma unroll
    for (int q = 0; q < INP / 4; ++q) {
        float4 v = xin[q];
        x[q * 4 + 0] = v.x; x[q * 4 + 1] = v.y;
        x[q * 4 + 2] = v.z; x[q * 4 + 3] = v.w;
    }

    // ---- three parameter nets; weights read via uniform (scalar) loads ----
    float vals[3];
    #pragma unroll 1
    for (int n = 0; n < 3; ++n) {
        float h[HL];
        #pragma unroll
        for (int k = 0; k < HL; ++k) {
            float acc = b0[n * HL + k];
            #pragma unroll
            for (int i = 0; i < INP; ++i)
                acc = fmaf(x[i], W0[(n * HL + k) * INP + i], acc);
            h[k] = tanhf(acc);
        }
        #pragma unroll 1
        for (int l = 0; l < NL; ++l) {
            float h2[HL];
            #pragma unroll
            for (int k = 0; k < HL; ++k) {
                float acc = bh[(n * NL + l) * HL + k];
                #pragma unroll
                for (int i = 0; i < HL; ++i)
                    acc = fmaf(h[i], Wh[((n * NL + l) * HL + k) * HL + i], acc);
                h2[k] = tanhf(acc);
            }
            #pragma unroll
            for (int k = 0; k < HL; ++k) h[k] = h2[k];
        }
        float acc = bo[n];
        #pragma unroll
        for (int i = 0; i < HL; ++i)
            acc = fmaf(h[i], Wo[n * HL + i], acc);
        // stable softplus
        vals[n] = fmaxf(acc, 0.0f) + log1pf(expf(-fabsf(acc)));
    }

    const float gamma = vals[0];
    const float beta  = vals[1];
    const float I0    = vals[2];

    float S = NPOP - I0;
    float I = I0;
    const float bn = beta * (1.0f / NPOP);

    out[b] = I;   // t = 0

    float tcur = times[0];          // uniform -> scalar load
    size_t ofs = (size_t)BSZ + (size_t)b;

    auto step = [&](float dt) {
        const float hdt = 0.5f * dt;
        float flux, rec;
        flux = bn * S * I;  rec = gamma * I;
        const float k1S = -flux, k1I = flux - rec;
        float aS = fmaf(hdt, k1S, S), aI = fmaf(hdt, k1I, I);
        flux = bn * aS * aI;  rec = gamma * aI;
        const float k2S = -flux, k2I = flux - rec;
        aS = fmaf(hdt, k2S, S);  aI = fmaf(hdt, k2I, I);
        flux = bn * aS * aI;  rec = gamma * aI;
        const float k3S = -flux, k3I = flux - rec;
        aS = fmaf(dt, k3S, S);  aI = fmaf(dt, k3I, I);
        flux = bn * aS * aI;  rec = gamma * aI;
        const float k4S = -flux, k4I = flux - rec;
        const float c = dt * (1.0f / 6.0f);
        S = fmaf(c, k1S + 2.0f * k2S + 2.0f * k3S + k4S, S);
        I = fmaf(c, k1I + 2.0f * k2I + 2.0f * k3I + k4I, I);
    };

    // ---- 199 RK4 steps: 24 blocks of 8 + tail of 7 ----
    int t = 0;
    #pragma unroll 1
    for (int blk = 0; blk < 24; ++blk) {
        float iv[8];
        #pragma unroll
        for (int u = 0; u < 8; ++u) {
            const float tn = times[t + u + 1];   // uniform -> scalar load
            step(tn - tcur);
            tcur = tn;
            iv[u] = I;
        }
        #pragma unroll
        for (int u = 0; u < 8; ++u)
            out[ofs + (size_t)u * BSZ] = iv[u];
        ofs += (size_t)(8 * BSZ);
        t += 8;
    }
    #pragma unroll
    for (int u = 0; u < 7; ++u) {
        const float tn = times[t + u + 1];
        step(tn - tcur);
        tcur = tn;
        out[ofs + (size_t)u * BSZ] = I;
    }
}

extern "C" void kernel_launch(void* const* d_in, const int* in_sizes, int n_in,
                              void* d_out, int out_size, void* d_ws, size_t ws_size,
                              hipStream_t stream) {
    const float* data  = (const float*)d_in[0];
    const float* times = (const float*)d_in[1];
    const float* W0    = (const float*)d_in[2];
    const float* b0    = (const float*)d_in[3];
    const float* Wh    = (const float*)d_in[4];
    const float* bh    = (const float*)d_in[5];
    const float* Wo    = (const float*)d_in[6];
    const float* bo    = (const float*)d_in[7];
    float* out = (float*)d_out;

    sir_kernel<<<BSZ / 256, 256, 0, stream>>>(data, times, W0, b0, Wh, bh, Wo, bo, out);
}

// Round 3
// 59.301 us; speedup vs baseline: 1.0188x; 1.0188x over previous
//
#include <hip/hip_runtime.h>
#include <math.h>

#define BSZ   65536
#define INP   16
#define HL    10
#define NL    3
#define TT    200
#define NPOP  8600000.0f

#define CH    16           // steps per chunk
#define NCH   12           // 12*16 = 192 full-chunk steps
#define TAIL  7            // 199 - 192

__global__ __launch_bounds__(256, 1) void sir_kernel(
    const float* __restrict__ data,   // B x IN
    const float* __restrict__ times,  // T
    const float* __restrict__ W0,     // 3 x HL x IN
    const float* __restrict__ b0,     // 3 x HL
    const float* __restrict__ Wh,     // 3 x NL x HL x HL
    const float* __restrict__ bh,     // 3 x NL x HL
    const float* __restrict__ Wo,     // 3 x 1 x HL
    const float* __restrict__ bo,     // 3 x 1
    float* __restrict__ out)          // T x B
{
    __shared__ float sdt[TT];         // sdt[t] = times[t+1]-times[t], 199 used (pad to 200)

    const int tid = threadIdx.x;
    if (tid < TT - 1) sdt[tid] = times[tid + 1] - times[tid];
    if (tid == TT - 1) sdt[tid] = 0.0f;
    __syncthreads();

    const int b = blockIdx.x * 256 + tid;

    // ---- input row: 4x float4, coalesced ----
    float x[INP];
    const float4* xin = reinterpret_cast<const float4*>(data + (size_t)b * INP);
    #pragma unroll
    for (int q = 0; q < INP / 4; ++q) {
        float4 v = xin[q];
        x[q * 4 + 0] = v.x; x[q * 4 + 1] = v.y;
        x[q * 4 + 2] = v.z; x[q * 4 + 3] = v.w;
    }

    // ---- three parameter nets (weights uniform -> scalar loads) ----
    float vals[3];
    #pragma unroll 1
    for (int n = 0; n < 3; ++n) {
        float h[HL];
        #pragma unroll
        for (int k = 0; k < HL; ++k) {
            float acc = b0[n * HL + k];
            #pragma unroll
            for (int i = 0; i < INP; ++i)
                acc = fmaf(x[i], W0[(n * HL + k) * INP + i], acc);
            h[k] = tanhf(acc);
        }
        #pragma unroll 1
        for (int l = 0; l < NL; ++l) {
            float h2[HL];
            #pragma unroll
            for (int k = 0; k < HL; ++k) {
                float acc = bh[(n * NL + l) * HL + k];
                #pragma unroll
                for (int i = 0; i < HL; ++i)
                    acc = fmaf(h[i], Wh[((n * NL + l) * HL + k) * HL + i], acc);
                h2[k] = tanhf(acc);
            }
            #pragma unroll
            for (int k = 0; k < HL; ++k) h[k] = h2[k];
        }
        float acc = bo[n];
        #pragma unroll
        for (int i = 0; i < HL; ++i)
            acc = fmaf(h[i], Wo[n * HL + i], acc);
        vals[n] = fmaxf(acc, 0.0f) + log1pf(expf(-fabsf(acc)));  // stable softplus
    }

    const float gamma = vals[0];
    const float beta  = vals[1];
    const float I0    = vals[2];

    float S = NPOP - I0;
    float I = I0;
    const float bn = beta * (1.0f / NPOP);

    out[b] = I;   // t = 0

    auto step = [&](float dt) {
        const float hdt = 0.5f * dt;
        float flux, rec;
        flux = bn * S * I;  rec = gamma * I;
        const float k1S = -flux, k1I = flux - rec;
        float aS = fmaf(hdt, k1S, S), aI = fmaf(hdt, k1I, I);
        flux = bn * aS * aI;  rec = gamma * aI;
        const float k2S = -flux, k2I = flux - rec;
        aS = fmaf(hdt, k2S, S);  aI = fmaf(hdt, k2I, I);
        flux = bn * aS * aI;  rec = gamma * aI;
        const float k3S = -flux, k3I = flux - rec;
        aS = fmaf(dt, k3S, S);  aI = fmaf(dt, k3I, I);
        flux = bn * aS * aI;  rec = gamma * aI;
        const float k4S = -flux, k4I = flux - rec;
        const float c = dt * (1.0f / 6.0f);
        S = fmaf(c, k1S + 2.0f * k2S + 2.0f * k3S + k4S, S);
        I = fmaf(c, k1I + 2.0f * k2I + 2.0f * k3I + k4I, I);
    };

    const float4* sdt4 = reinterpret_cast<const float4*>(sdt);

    // ---- 12 chunks of 16 pure-ALU steps ----
    #pragma unroll 1
    for (int c = 0; c < NCH; ++c) {
        const int t0 = c * CH;

        // hoisted chunk dts: 4x float4 LDS broadcast reads, one lgkm wait
        float d[CH];
        #pragma unroll
        for (int q = 0; q < CH / 4; ++q) {
            float4 v = sdt4[t0 / 4 + q];
            d[q * 4 + 0] = v.x; d[q * 4 + 1] = v.y;
            d[q * 4 + 2] = v.z; d[q * 4 + 3] = v.w;
        }

        float sbuf[CH];
        #pragma unroll
        for (int u = 0; u < CH; ++u) {
            step(d[u]);
            sbuf[u] = I;
        }

        // burst stores: uniform base (SGPR) + per-lane b offset
        #pragma unroll
        for (int u = 0; u < CH; ++u) {
            float* p = out + (size_t)(t0 + u + 1) * BSZ;
            p[b] = sbuf[u];
        }
    }

    // ---- tail: 7 steps ----
    {
        const int t0 = NCH * CH;
        float d[TAIL];
        #pragma unroll
        for (int u = 0; u < TAIL; ++u) d[u] = sdt[t0 + u];

        float sbuf[TAIL];
        #pragma unroll
        for (int u = 0; u < TAIL; ++u) {
            step(d[u]);
            sbuf[u] = I;
        }
        #pragma unroll
        for (int u = 0; u < TAIL; ++u) {
            float* p = out + (size_t)(t0 + u + 1) * BSZ;
            p[b] = sbuf[u];
        }
    }
}

extern "C" void kernel_launch(void* const* d_in, const int* in_sizes, int n_in,
                              void* d_out, int out_size, void* d_ws, size_t ws_size,
                              hipStream_t stream) {
    const float* data  = (const float*)d_in[0];
    const float* times = (const float*)d_in[1];
    const float* W0    = (const float*)d_in[2];
    const float* b0    = (const float*)d_in[3];
    const float* Wh    = (const float*)d_in[4];
    const float* bh    = (const float*)d_in[5];
    const float* Wo    = (const float*)d_in[6];
    const float* bo    = (const float*)d_in[7];
    float* out = (float*)d_out;

    sir_kernel<<<BSZ / 256, 256, 0, stream>>>(data, times, W0, b0, Wh, bh, Wo, bo, out);
}